// Round 5
// baseline (81.834 us; speedup 1.0000x reference)
//
#include <hip/hip_runtime.h>
#include <hip/hip_bf16.h>
#include <hip/hip_cooperative_groups.h>
#include <cstdint>
#include <cstddef>

namespace cg = cooperative_groups;

typedef __bf16 bf16_t;
typedef __bf16 bf16x8 __attribute__((ext_vector_type(8)));
typedef __bf16 bf16x4 __attribute__((ext_vector_type(4)));
typedef float f32x4 __attribute__((ext_vector_type(4)));

#define NNODES 4096
#define EMB 512
#define NH 8
#define DT 64
#define DTOT 512

// LDS pool: max(F1: 64*68*4 + 2*8192 = 33792, F2: 32768, G2: 16384)
#define POOL_BYTES 33792

__device__ __forceinline__ void async_copy16(void* lds, const void* gsrc) {
  __builtin_amdgcn_global_load_lds(
      (const __attribute__((address_space(1))) void*)gsrc,
      (__attribute__((address_space(3))) void*)lds, 16, 0, 0);
}

__device__ __forceinline__ bool beta_all_zero(const float* __restrict__ beta) {
  bool z = true;
#pragma unroll
  for (int h = 0; h < NH; ++h) z = z && (beta[h] == 0.0f);
  return z;
}

__global__ __launch_bounds__(256, 2) void mega_kernel(
    const float* __restrict__ x, const float* __restrict__ adj,
    const float* __restrict__ wq, const float* __restrict__ bq,
    const float* __restrict__ wk, const float* __restrict__ bk,
    const float* __restrict__ wv, const float* __restrict__ bv,
    const float* __restrict__ wo, const float* __restrict__ bo,
    const float* __restrict__ alpha, const float* __restrict__ beta,
    float* __restrict__ out,
    bf16_t* __restrict__ xb, bf16_t* __restrict__ wqkvT,
    bf16_t* __restrict__ woT, bf16_t* __restrict__ w_effT,
    float* __restrict__ b_eff, bf16_t* __restrict__ qkv,
    bf16_t* __restrict__ z) {
  __shared__ __align__(16) char pool[POOL_BYTES];
  __shared__ float bvs[64];
  cg::grid_group grid = cg::this_grid();
  const int tid = threadIdx.x, l = tid & 63, w = tid >> 6;
  const int wm = w >> 1, wn = w & 1;
  const int bid = blockIdx.x;
  const bool fast = beta_all_zero(beta);

  if (fast) {
    // ================= F1: W_effT[n][k] = sum_d wo[d][n]*alpha[d>>6]*wv[k][d]
    //                  + b_eff[n] = bo[n] + sum_d bv[d]*alpha*wo[d][n]
    if (bid < 64) {
      float* ftile = (float*)pool;                    // [64][68] fp32 (wo tile)
      bf16_t* sA = (bf16_t*)(pool + 17408);           // [64 n][64 d] swz
      bf16_t* sB = (bf16_t*)(pool + 17408 + 8192);    // [64 k][64 d] swz
      const int nt = bid >> 3, kt = bid & 7;
      const int n0 = nt * 64, k0 = kt * 64;
      f32x4 acc[2][2];
#pragma unroll
      for (int m = 0; m < 2; ++m)
#pragma unroll
        for (int n = 0; n < 2; ++n) acc[m][n] = f32x4{0.f, 0.f, 0.f, 0.f};
      float bias_acc = 0.f;

      for (int dstep = 0; dstep < 8; ++dstep) {
        const int d0 = dstep * 64;
        const float sc = alpha[dstep];  // head = d>>6 = dstep for this d-chunk
        // stage ftile[d][n] = wo[d0+d][n0+n] (coalesced)
#pragma unroll
        for (int j = 0; j < 4; ++j) {
          int r = j * 16 + (tid >> 4), c4 = tid & 15;
          float4 v = *(const float4*)&wo[(size_t)(d0 + r) * EMB + n0 + c4 * 4];
          *(float4*)&ftile[r * 68 + c4 * 4] = v;
        }
        if (tid < 64) bvs[tid] = bv[d0 + tid];
        __syncthreads();
        // sA[n][d] (transpose from ftile) and sB[k][d] (direct from wv, *alpha)
#pragma unroll
        for (int j = 0; j < 2; ++j) {
          int s = tid * 2 + j, r = s >> 3, c = s & 7;
          // A: n=r, chunk c over d
          bf16x8 oa;
#pragma unroll
          for (int e = 0; e < 8; ++e) oa[e] = (bf16_t)ftile[(c * 8 + e) * 68 + r];
          *(bf16x8*)&sA[r * 64 + ((c ^ (r & 7)) << 3)] = oa;
          // B: k=r
          const float* srcb = &wv[(size_t)(k0 + r) * EMB + d0 + c * 8];
          float4 v0 = *(const float4*)srcb, v1 = *(const float4*)(srcb + 4);
          bf16x8 ob = {(bf16_t)(v0.x * sc), (bf16_t)(v0.y * sc),
                       (bf16_t)(v0.z * sc), (bf16_t)(v0.w * sc),
                       (bf16_t)(v1.x * sc), (bf16_t)(v1.y * sc),
                       (bf16_t)(v1.z * sc), (bf16_t)(v1.w * sc)};
          *(bf16x8*)&sB[r * 64 + ((c ^ (r & 7)) << 3)] = ob;
        }
        __syncthreads();
#pragma unroll
        for (int ks = 0; ks < 2; ++ks) {
          bf16x8 af[2], bfv[2];
#pragma unroll
          for (int m = 0; m < 2; ++m) {
            int row = wm * 32 + m * 16 + (l & 15);
            af[m] = *(const bf16x8*)&sA[row * 64 + (((ks * 4 + (l >> 4)) ^ (row & 7)) << 3)];
          }
#pragma unroll
          for (int n = 0; n < 2; ++n) {
            int row = wn * 32 + n * 16 + (l & 15);
            bfv[n] = *(const bf16x8*)&sB[row * 64 + (((ks * 4 + (l >> 4)) ^ (row & 7)) << 3)];
          }
#pragma unroll
          for (int m = 0; m < 2; ++m)
#pragma unroll
            for (int n = 0; n < 2; ++n)
              acc[m][n] = __builtin_amdgcn_mfma_f32_16x16x32_bf16(af[m], bfv[n], acc[m][n], 0, 0, 0);
        }
        if (kt == 0 && tid < 64) {
          float s = 0.f;
          for (int dl = 0; dl < 64; ++dl) s += bvs[dl] * ftile[dl * 68 + tid];
          bias_acc += sc * s;
        }
        __syncthreads();
      }
#pragma unroll
      for (int m = 0; m < 2; ++m) {
        int r0 = n0 + wm * 32 + m * 16 + ((l >> 4) << 2);
#pragma unroll
        for (int nn = 0; nn < 2; ++nn) {
          int col = k0 + wn * 32 + nn * 16 + (l & 15);
#pragma unroll
          for (int r = 0; r < 4; ++r)
            w_effT[(size_t)(r0 + r) * EMB + col] = (bf16_t)acc[m][nn][r];
        }
      }
      if (kt == 0 && tid < 64) b_eff[n0 + tid] = bo[n0 + tid] + bias_acc;
    }
    grid.sync();
    // ================= F2: out[m][n] = sum_k x[m][k]*w_effT[n][k] + b_eff[n]
    {
      bf16_t* sA = (bf16_t*)pool;             // [2][64*64]
      bf16_t* sB = (bf16_t*)(pool + 16384);   // [2][64*64]
      const int q = bid >> 3, xcd = bid & 7;
      const int m0 = (xcd * 8 + (q >> 3)) * 64, n0 = (q & 7) * 64;
      f32x4 acc[2][2];
#pragma unroll
      for (int m = 0; m < 2; ++m)
#pragma unroll
        for (int n = 0; n < 2; ++n) acc[m][n] = f32x4{0.f, 0.f, 0.f, 0.f};
      float4 avA[2][2];

#define LOADA(t)                                                              \
  {                                                                           \
    _Pragma("unroll") for (int j = 0; j < 2; ++j) {                           \
      int s = tid * 2 + j, r = s >> 3, c = s & 7;                             \
      const float* src = &x[(size_t)(m0 + r) * EMB + (t) * 64 + c * 8];       \
      avA[j][0] = *(const float4*)src;                                        \
      avA[j][1] = *(const float4*)(src + 4);                                  \
    }                                                                         \
  }
#define WRITEA(dst)                                                           \
  {                                                                           \
    _Pragma("unroll") for (int j = 0; j < 2; ++j) {                           \
      int s = tid * 2 + j, r = s >> 3, c = s & 7;                             \
      bf16x8 o = {(bf16_t)avA[j][0].x, (bf16_t)avA[j][0].y,                   \
                  (bf16_t)avA[j][0].z, (bf16_t)avA[j][0].w,                   \
                  (bf16_t)avA[j][1].x, (bf16_t)avA[j][1].y,                   \
                  (bf16_t)avA[j][1].z, (bf16_t)avA[j][1].w};                  \
      *(bf16x8*)&(dst)[r * 64 + ((c ^ (r & 7)) << 3)] = o;                    \
    }                                                                         \
  }
#define STAGEB(t, dst)                                                        \
  {                                                                           \
    _Pragma("unroll") for (int j = 0; j < 2; ++j) {                           \
      int base = (w * 2 + j) * 64, s = base + l, r = s >> 3, c = s & 7;       \
      async_copy16((dst) + base * 8,                                          \
                   &w_effT[(size_t)(n0 + r) * EMB + (t) * 64 + ((c ^ (r & 7)) << 3)]); \
    }                                                                         \
  }

      LOADA(0)
      STAGEB(0, sB)
      WRITEA(sA)
      __syncthreads();
      for (int t = 0; t < 8; ++t) {
        const int cur = t & 1;
        bf16_t* cA = sA + cur * 4096;
        bf16_t* cB = sB + cur * 4096;
        if (t < 7) {
          LOADA(t + 1)
          STAGEB(t + 1, sB + (cur ^ 1) * 4096)
        }
#pragma unroll
        for (int ks = 0; ks < 2; ++ks) {
          bf16x8 af[2], bfv[2];
#pragma unroll
          for (int m = 0; m < 2; ++m) {
            int row = wm * 32 + m * 16 + (l & 15);
            af[m] = *(const bf16x8*)&cA[row * 64 + (((ks * 4 + (l >> 4)) ^ (row & 7)) << 3)];
          }
#pragma unroll
          for (int n = 0; n < 2; ++n) {
            int row = wn * 32 + n * 16 + (l & 15);
            bfv[n] = *(const bf16x8*)&cB[row * 64 + (((ks * 4 + (l >> 4)) ^ (row & 7)) << 3)];
          }
#pragma unroll
          for (int m = 0; m < 2; ++m)
#pragma unroll
            for (int n = 0; n < 2; ++n)
              acc[m][n] = __builtin_amdgcn_mfma_f32_16x16x32_bf16(af[m], bfv[n], acc[m][n], 0, 0, 0);
        }
        if (t < 7) WRITEA(sA + (cur ^ 1) * 4096)
        __syncthreads();
      }
#pragma unroll
      for (int m = 0; m < 2; ++m) {
        int r0 = m0 + wm * 32 + m * 16 + ((l >> 4) << 2);
#pragma unroll
        for (int nn = 0; nn < 2; ++nn) {
          int col = n0 + wn * 32 + nn * 16 + (l & 15);
          float bias = b_eff[col];
#pragma unroll
          for (int r = 0; r < 4; ++r)
            out[(size_t)(r0 + r) * DTOT + col] = acc[m][nn][r] + bias;
        }
      }
#undef LOADA
#undef WRITEA
#undef STAGEB
    }
    return;
  }

  // ===================== GENERAL PATH (correct for any alpha/beta) ==========
  // G1: x->bf16 + wq/wk/wv/wo transposes
  {
#pragma unroll
    for (int it = 0; it < 4; ++it) {
      int i = bid * 1024 + it * 256 + tid;
      float4 v = reinterpret_cast<const float4*>(x)[i];
      bf16x4 o = {(bf16_t)v.x, (bf16_t)v.y, (bf16_t)v.z, (bf16_t)v.w};
      reinterpret_cast<bf16x4*>(xb)[i] = o;
    }
    if (bid < 256) {
      float* ftile = (float*)pool;
      int mat = bid >> 6, t2 = bid & 63;
      const float* src = mat == 0 ? wq : mat == 1 ? wk : mat == 2 ? wv : wo;
      int kb = (t2 >> 3) << 6, nb = (t2 & 7) << 6;
      int c = tid & 63, r0 = tid >> 6;
      for (int r = r0; r < 64; r += 4)
        ftile[r * 68 + c] = src[(size_t)(kb + r) * EMB + nb + c];
      __syncthreads();
      bf16_t* dst = mat < 3 ? wqkvT + (size_t)mat * EMB * DTOT : woT;
      for (int r = r0; r < 64; r += 4)
        dst[(size_t)(nb + r) * EMB + kb + c] = (bf16_t)ftile[c * 68 + r];
    }
  }
  grid.sync();
  // G2: QKV projection GEMM (384 tiles of 128x128, K=512)
  if (bid < 384) {
    bf16_t* sA = (bf16_t*)pool;
    bf16_t* sB = (bf16_t*)(pool + 8192);
    const int arow0 = (bid & 31) * 128, bcol0 = (bid >> 5) * 128;
    f32x4 acc[4][4];
#pragma unroll
    for (int m = 0; m < 4; ++m)
#pragma unroll
      for (int n = 0; n < 4; ++n) acc[m][n] = f32x4{0.f, 0.f, 0.f, 0.f};
    for (int kt = 0; kt < 512; kt += 32) {
#pragma unroll
      for (int i = 0; i < 2; ++i) {
        int row = (i << 6) + (w << 4) + (l >> 2);
        int cole = (l & 3) << 3;
        int ldso = i * 2048 + w * 512;
        async_copy16(&sA[ldso], &xb[(size_t)(arow0 + row) * 512 + kt + cole]);
        async_copy16(&sB[ldso], &wqkvT[(size_t)(bcol0 + row) * 512 + kt + cole]);
      }
      __syncthreads();
      bf16x8 af[4], bfr[4];
#pragma unroll
      for (int m = 0; m < 4; ++m)
        af[m] = *(const bf16x8*)&sA[(wm * 64 + m * 16 + (l & 15)) * 32 + ((l >> 4) << 3)];
#pragma unroll
      for (int n = 0; n < 4; ++n)
        bfr[n] = *(const bf16x8*)&sB[(wn * 64 + n * 16 + (l & 15)) * 32 + ((l >> 4) << 3)];
#pragma unroll
      for (int m = 0; m < 4; ++m)
#pragma unroll
        for (int n = 0; n < 4; ++n)
          acc[m][n] = __builtin_amdgcn_mfma_f32_16x16x32_bf16(af[m], bfr[n], acc[m][n], 0, 0, 0);
      __syncthreads();
    }
#pragma unroll
    for (int m = 0; m < 4; ++m) {
      int row0 = arow0 + wm * 64 + m * 16 + ((l >> 4) << 2);
#pragma unroll
      for (int n = 0; n < 4; ++n) {
        int col = bcol0 + wn * 64 + n * 16 + (l & 15);
        int mi = col >> 9, hc = col & 511;
        const float* bp = mi == 0 ? bq : mi == 1 ? bk : bv;
        float bias = bp[hc];
        int head = hc >> 6, tt = hc & 63;
        bf16_t* base = qkv + (((size_t)mi * NH + head) * NNODES) * DT + tt;
#pragma unroll
        for (int r = 0; r < 4; ++r)
          base[(size_t)(row0 + r) * DT] = (bf16_t)(acc[m][n][r] + bias);
      }
    }
  }
  grid.sync();
  // G3: flash attention, 1024 (block,head) units over 512 blocks x 2
  {
    float* qs = (float*)pool;           // [4][64]
    float* ps = (float*)(pool + 1024);  // [4][64]
    const int wv_ = w;
#pragma unroll
    for (int it = 0; it < 2; ++it) {
      int u = it * 512 + bid;
      int h = u >> 7, bx = u & 127;
      const float a = alpha[h], b = beta[h];
      const size_t hoff = (size_t)h * NNODES * DT;
      const bf16_t* Q = qkv + hoff;
      const bf16_t* Kh = qkv + (size_t)NH * NNODES * DT + hoff;
      const bf16_t* V = qkv + (size_t)2 * NH * NNODES * DT + hoff;
      for (int i = bx * 4 + wv_; i < NNODES; i += 512) {
        if (b == 0.0f) {
          z[(size_t)i * DTOT + h * DT + l] = (bf16_t)(a * (float)V[(size_t)i * DT + l]);
          continue;
        }
        qs[wv_ * 64 + l] = (float)Q[(size_t)i * DT + l];
        float mr = -__builtin_inff(), sr = 0.f, zacc = 0.f, sii = -__builtin_inff();
        const float* adjrow = adj + ((size_t)h * NNODES + i) * NNODES;
        __syncthreads();
        for (int c0 = 0; c0 < NNODES; c0 += 64) {
          int jj = c0 + l;
          float s = 0.f;
          const bf16_t* kp = Kh + (size_t)jj * DT;
#pragma unroll
          for (int d = 0; d < 64; ++d) s += qs[wv_ * 64 + d] * (float)kp[d];
          s = s * 0.125f + adjrow[jj];
          if ((i >> 6) == (c0 >> 6)) sii = __shfl(s, i & 63, 64);
          float cm = s;
#pragma unroll
          for (int o = 32; o; o >>= 1) cm = fmaxf(cm, __shfl_xor(cm, o, 64));
          float mn = fmaxf(mr, cm);
          float scale = expf(mr - mn);
          sr *= scale;
          zacc *= scale;
          float p = expf(s - mn);
          float cs = p;
#pragma unroll
          for (int o = 32; o; o >>= 1) cs += __shfl_xor(cs, o, 64);
          sr += cs;
          mr = mn;
          ps[wv_ * 64 + l] = p;
          __syncthreads();
          float za = 0.f;
          for (int j2 = 0; j2 < 64; ++j2)
            za += ps[wv_ * 64 + j2] * (float)V[(size_t)(c0 + j2) * DT + l];
          zacc += za;
          __syncthreads();
        }
        float pii = expf(sii - mr) / sr;
        float vd = (float)V[(size_t)i * DT + l];
        float zd = b * (zacc / sr) + (a - b * pii) * vd;
        z[(size_t)i * DTOT + h * DT + l] = (bf16_t)zd;
      }
    }
  }
  grid.sync();
  // G4: output GEMM (128 tiles of 128x128): out = z @ woT^T + bo
  if (bid < 128) {
    bf16_t* sA = (bf16_t*)pool;
    bf16_t* sB = (bf16_t*)(pool + 8192);
    const int arow0 = (bid & 31) * 128, bcol0 = (bid >> 5) * 128;
    f32x4 acc[4][4];
#pragma unroll
    for (int m = 0; m < 4; ++m)
#pragma unroll
      for (int n = 0; n < 4; ++n) acc[m][n] = f32x4{0.f, 0.f, 0.f, 0.f};
    for (int kt = 0; kt < 512; kt += 32) {
#pragma unroll
      for (int i = 0; i < 2; ++i) {
        int row = (i << 6) + (w << 4) + (l >> 2);
        int cole = (l & 3) << 3;
        int ldso = i * 2048 + w * 512;
        async_copy16(&sA[ldso], &z[(size_t)(arow0 + row) * 512 + kt + cole]);
        async_copy16(&sB[ldso], &woT[(size_t)(bcol0 + row) * 512 + kt + cole]);
      }
      __syncthreads();
      bf16x8 af[4], bfr[4];
#pragma unroll
      for (int m = 0; m < 4; ++m)
        af[m] = *(const bf16x8*)&sA[(wm * 64 + m * 16 + (l & 15)) * 32 + ((l >> 4) << 3)];
#pragma unroll
      for (int n = 0; n < 4; ++n)
        bfr[n] = *(const bf16x8*)&sB[(wn * 64 + n * 16 + (l & 15)) * 32 + ((l >> 4) << 3)];
#pragma unroll
      for (int m = 0; m < 4; ++m)
#pragma unroll
        for (int n = 0; n < 4; ++n)
          acc[m][n] = __builtin_amdgcn_mfma_f32_16x16x32_bf16(af[m], bfr[n], acc[m][n], 0, 0, 0);
      __syncthreads();
    }
#pragma unroll
    for (int m = 0; m < 4; ++m) {
      int row0 = arow0 + wm * 64 + m * 16 + ((l >> 4) << 2);
#pragma unroll
      for (int n = 0; n < 4; ++n) {
        int col = bcol0 + wn * 64 + n * 16 + (l & 15);
        float bias = bo[col];
#pragma unroll
        for (int r = 0; r < 4; ++r)
          out[(size_t)(row0 + r) * DTOT + col] = acc[m][n][r] + bias;
      }
    }
  }
}

// ---------------------------------------------------------------------------
extern "C" void kernel_launch(void* const* d_in, const int* in_sizes, int n_in,
                              void* d_out, int out_size, void* d_ws, size_t ws_size,
                              hipStream_t stream) {
  const float* x     = (const float*)d_in[0];
  const float* adj   = (const float*)d_in[1];
  const float* wq    = (const float*)d_in[2];
  const float* bq    = (const float*)d_in[3];
  const float* wk    = (const float*)d_in[4];
  const float* bk    = (const float*)d_in[5];
  const float* wv    = (const float*)d_in[6];
  const float* bv    = (const float*)d_in[7];
  const float* wo    = (const float*)d_in[8];
  const float* bo    = (const float*)d_in[9];
  const float* alpha = (const float*)d_in[10];
  const float* beta  = (const float*)d_in[11];
  float* out = (float*)d_out;
  char* ws = (char*)d_ws;

  bf16_t* xb     = (bf16_t*)(ws);                 // 4 MB
  bf16_t* wqkvT  = (bf16_t*)(ws + 4194304u);      // 1.5 MB
  bf16_t* woT    = (bf16_t*)(ws + 5767168u);      // 0.5 MB
  bf16_t* w_effT = (bf16_t*)(ws + 6291456u);      // 0.5 MB
  float*  b_eff  = (float*)(ws + 6815744u);       // 2 KB
  bf16_t* qkv    = (bf16_t*)(ws + 8388608u);      // 12 MB
  bf16_t* z      = (bf16_t*)(ws + 20971520u);     // 4 MB

  void* args[] = {&x, &adj, &wq, &bq, &wk, &bk, &wv, &bv, &wo, &bo,
                  &alpha, &beta, &out, &xb, &wqkvT, &woT, &w_effT,
                  &b_eff, &qkv, &z};
  hipLaunchCooperativeKernel((void*)mega_kernel, dim3(512), dim3(256),
                             args, 0, stream);
}

// Round 6
// 30.701 us; speedup vs baseline: 2.6656x; 2.6656x over previous
//
#include <hip/hip_runtime.h>
#include <hip/hip_bf16.h>
#include <cstdint>
#include <cstddef>

typedef __bf16 bf16_t;
typedef __bf16 bf16x8 __attribute__((ext_vector_type(8)));
typedef __bf16 bf16x4 __attribute__((ext_vector_type(4)));
typedef float f32x4 __attribute__((ext_vector_type(4)));

#define NNODES 4096
#define EMB 512
#define NH 8
#define DT 64
#define DTOT 512

__device__ __forceinline__ void async_copy16(void* lds, const void* gsrc) {
  __builtin_amdgcn_global_load_lds(
      (const __attribute__((address_space(1))) void*)gsrc,
      (__attribute__((address_space(3))) void*)lds, 16, 0, 0);
}

__device__ __forceinline__ bool beta_all_zero(const float* __restrict__ beta) {
  bool z = true;
#pragma unroll
  for (int h = 0; h < NH; ++h) z = z && (beta[h] == 0.0f);
  return z;
}

// ===========================================================================
// K1 (grid 320):
//  fast:    blocks 0..63 compose w_effT[n][k] = sum_d wo[d][n]*alpha[d>>6]*wv[k][d]
//           and b_eff[n] = bo[n] + sum_d bv[d]*alpha[d>>6]*wo[d][n]
//  general: blocks 0..255 cvt x->bf16; blocks 256..319 transpose wq/wk/wv/wo
__global__ __launch_bounds__(256, 2) void k1_prep_compose(
    const float* __restrict__ x,
    const float* __restrict__ wq, const float* __restrict__ wk,
    const float* __restrict__ wv, const float* __restrict__ wo,
    const float* __restrict__ bv, const float* __restrict__ bo,
    const float* __restrict__ alpha, const float* __restrict__ beta,
    bf16_t* __restrict__ xb, bf16_t* __restrict__ wqkvT,
    bf16_t* __restrict__ woT, bf16_t* __restrict__ w_effT,
    float* __restrict__ b_eff) {
  __shared__ __align__(16) char pool[33792];
  __shared__ float bvs[64];
  const int tid = threadIdx.x, l = tid & 63, w = tid >> 6;
  const int wm = w >> 1, wn = w & 1;
  const int bid = blockIdx.x;

  if (beta_all_zero(beta)) {
    if (bid >= 64) return;
    float* ftile = (float*)pool;                  // [64][68] fp32 wo tile
    bf16_t* sA = (bf16_t*)(pool + 17408);         // [64 n][64 d] swz
    bf16_t* sB = (bf16_t*)(pool + 17408 + 8192);  // [64 k][64 d] swz
    const int nt = bid >> 3, kt = bid & 7;
    const int n0 = nt * 64, k0 = kt * 64;
    f32x4 acc[2][2];
#pragma unroll
    for (int m = 0; m < 2; ++m)
#pragma unroll
      for (int n = 0; n < 2; ++n) acc[m][n] = f32x4{0.f, 0.f, 0.f, 0.f};
    float bias_acc = 0.f;

    for (int dstep = 0; dstep < 8; ++dstep) {
      const int d0 = dstep * 64;
      const float sc = alpha[dstep];
#pragma unroll
      for (int j = 0; j < 4; ++j) {
        int r = j * 16 + (tid >> 4), c4 = tid & 15;
        float4 v = *(const float4*)&wo[(size_t)(d0 + r) * EMB + n0 + c4 * 4];
        *(float4*)&ftile[r * 68 + c4 * 4] = v;
      }
      if (tid < 64) bvs[tid] = bv[d0 + tid];
      __syncthreads();
#pragma unroll
      for (int j = 0; j < 2; ++j) {
        int s = tid * 2 + j, r = s >> 3, c = s & 7;
        bf16x8 oa;
#pragma unroll
        for (int e = 0; e < 8; ++e) oa[e] = (bf16_t)ftile[(c * 8 + e) * 68 + r];
        *(bf16x8*)&sA[r * 64 + ((c ^ (r & 7)) << 3)] = oa;
        const float* srcb = &wv[(size_t)(k0 + r) * EMB + d0 + c * 8];
        float4 v0 = *(const float4*)srcb, v1 = *(const float4*)(srcb + 4);
        bf16x8 ob = {(bf16_t)(v0.x * sc), (bf16_t)(v0.y * sc),
                     (bf16_t)(v0.z * sc), (bf16_t)(v0.w * sc),
                     (bf16_t)(v1.x * sc), (bf16_t)(v1.y * sc),
                     (bf16_t)(v1.z * sc), (bf16_t)(v1.w * sc)};
        *(bf16x8*)&sB[r * 64 + ((c ^ (r & 7)) << 3)] = ob;
      }
      __syncthreads();
#pragma unroll
      for (int ks = 0; ks < 2; ++ks) {
        bf16x8 af[2], bfv[2];
#pragma unroll
        for (int m = 0; m < 2; ++m) {
          int row = wm * 32 + m * 16 + (l & 15);
          af[m] = *(const bf16x8*)&sA[row * 64 + (((ks * 4 + (l >> 4)) ^ (row & 7)) << 3)];
        }
#pragma unroll
        for (int n = 0; n < 2; ++n) {
          int row = wn * 32 + n * 16 + (l & 15);
          bfv[n] = *(const bf16x8*)&sB[row * 64 + (((ks * 4 + (l >> 4)) ^ (row & 7)) << 3)];
        }
#pragma unroll
        for (int m = 0; m < 2; ++m)
#pragma unroll
          for (int n = 0; n < 2; ++n)
            acc[m][n] = __builtin_amdgcn_mfma_f32_16x16x32_bf16(af[m], bfv[n], acc[m][n], 0, 0, 0);
      }
      if (kt == 0 && tid < 64) {
        float s = 0.f;
        for (int dl = 0; dl < 64; ++dl) s += bvs[dl] * ftile[dl * 68 + tid];
        bias_acc += sc * s;
      }
      __syncthreads();
    }
#pragma unroll
    for (int m = 0; m < 2; ++m) {
      int r0 = n0 + wm * 32 + m * 16 + ((l >> 4) << 2);
#pragma unroll
      for (int nn = 0; nn < 2; ++nn) {
        int col = k0 + wn * 32 + nn * 16 + (l & 15);
#pragma unroll
        for (int r = 0; r < 4; ++r)
          w_effT[(size_t)(r0 + r) * EMB + col] = (bf16_t)acc[m][nn][r];
      }
    }
    if (kt == 0 && tid < 64) b_eff[n0 + tid] = bo[n0 + tid] + bias_acc;
    return;
  }

  // ---- general prep ----
  if (bid < 256) {  // x -> bf16, 8 float4 per thread
#pragma unroll
    for (int it = 0; it < 8; ++it) {
      int i = bid * 2048 + it * 256 + tid;
      float4 v = reinterpret_cast<const float4*>(x)[i];
      bf16x4 o = {(bf16_t)v.x, (bf16_t)v.y, (bf16_t)v.z, (bf16_t)v.w};
      reinterpret_cast<bf16x4*>(xb)[i] = o;
    }
    return;
  }
  {
    float* ftile = (float*)pool;  // [64][68]
#pragma unroll
    for (int j = 0; j < 4; ++j) {
      int job = (bid - 256) * 4 + j;
      int mat = job >> 6, t2 = job & 63;
      const float* src = mat == 0 ? wq : mat == 1 ? wk : mat == 2 ? wv : wo;
      int kb = (t2 >> 3) << 6, nb = (t2 & 7) << 6;
      int c = tid & 63, r0 = tid >> 6;
      for (int r = r0; r < 64; r += 4)
        ftile[r * 68 + c] = src[(size_t)(kb + r) * EMB + nb + c];
      __syncthreads();
      bf16_t* dst = mat < 3 ? wqkvT + (size_t)mat * EMB * DTOT : woT;
      for (int r = r0; r < 64; r += 4)
        dst[(size_t)(nb + r) * EMB + kb + c] = (bf16_t)ftile[c * 68 + r];
      __syncthreads();
    }
  }
}

// ===========================================================================
// K2 (grid 512):
//  fast:    out[m][n] = sum_k x[m][k]*w_effT[n][k] + b_eff[n]
//           (fp32 x converted in-register; XOR-swizzled LDS; XCD-chunked)
//  general: QKV projection GEMM (blocks 0..383)
__global__ __launch_bounds__(256, 2) void k2_final_qkv(
    const float* __restrict__ x, const bf16_t* __restrict__ w_effT,
    const float* __restrict__ b_eff, const bf16_t* __restrict__ xb,
    const bf16_t* __restrict__ wqkvT,
    const float* __restrict__ bq, const float* __restrict__ bk,
    const float* __restrict__ bv, const float* __restrict__ beta,
    float* __restrict__ out, bf16_t* __restrict__ qkv) {
  __shared__ __align__(16) char pool[32768];
  const int tid = threadIdx.x, l = tid & 63, w = tid >> 6;
  const int wm = w >> 1, wn = w & 1;
  const int bid = blockIdx.x;

  if (beta_all_zero(beta)) {
    bf16_t* sA = (bf16_t*)pool;            // [2][64*64]
    bf16_t* sB = (bf16_t*)(pool + 16384);  // [2][64*64]
    const int q = bid >> 3, xcd = bid & 7;
    const int m0 = (xcd * 8 + (q >> 3)) * 64, n0 = (q & 7) * 64;
    f32x4 acc[2][2];
#pragma unroll
    for (int m = 0; m < 2; ++m)
#pragma unroll
      for (int n = 0; n < 2; ++n) acc[m][n] = f32x4{0.f, 0.f, 0.f, 0.f};
    float4 avA[2][2];

#define LOADA(t)                                                              \
  {                                                                           \
    _Pragma("unroll") for (int j = 0; j < 2; ++j) {                           \
      int s = tid * 2 + j, r = s >> 3, c = s & 7;                             \
      const float* src = &x[(size_t)(m0 + r) * EMB + (t) * 64 + c * 8];       \
      avA[j][0] = *(const float4*)src;                                        \
      avA[j][1] = *(const float4*)(src + 4);                                  \
    }                                                                         \
  }
#define WRITEA(dst)                                                           \
  {                                                                           \
    _Pragma("unroll") for (int j = 0; j < 2; ++j) {                           \
      int s = tid * 2 + j, r = s >> 3, c = s & 7;                             \
      bf16x8 o = {(bf16_t)avA[j][0].x, (bf16_t)avA[j][0].y,                   \
                  (bf16_t)avA[j][0].z, (bf16_t)avA[j][0].w,                   \
                  (bf16_t)avA[j][1].x, (bf16_t)avA[j][1].y,                   \
                  (bf16_t)avA[j][1].z, (bf16_t)avA[j][1].w};                  \
      *(bf16x8*)&(dst)[r * 64 + ((c ^ (r & 7)) << 3)] = o;                    \
    }                                                                         \
  }
#define STAGEB(t, dst)                                                        \
  {                                                                           \
    _Pragma("unroll") for (int j = 0; j < 2; ++j) {                           \
      int base = (w * 2 + j) * 64, s = base + l, r = s >> 3, c = s & 7;       \
      async_copy16((dst) + base * 8,                                          \
                   &w_effT[(size_t)(n0 + r) * EMB + (t) * 64 + ((c ^ (r & 7)) << 3)]); \
    }                                                                         \
  }

    LOADA(0)
    STAGEB(0, sB)
    WRITEA(sA)
    __syncthreads();
    for (int t = 0; t < 8; ++t) {
      const int cur = t & 1;
      bf16_t* cA = sA + cur * 4096;
      bf16_t* cB = sB + cur * 4096;
      if (t < 7) {
        LOADA(t + 1)
        STAGEB(t + 1, sB + (cur ^ 1) * 4096)
      }
#pragma unroll
      for (int ks = 0; ks < 2; ++ks) {
        bf16x8 af[2], bfv[2];
#pragma unroll
        for (int m = 0; m < 2; ++m) {
          int row = wm * 32 + m * 16 + (l & 15);
          af[m] = *(const bf16x8*)&cA[row * 64 + (((ks * 4 + (l >> 4)) ^ (row & 7)) << 3)];
        }
#pragma unroll
        for (int n = 0; n < 2; ++n) {
          int row = wn * 32 + n * 16 + (l & 15);
          bfv[n] = *(const bf16x8*)&cB[row * 64 + (((ks * 4 + (l >> 4)) ^ (row & 7)) << 3)];
        }
#pragma unroll
        for (int m = 0; m < 2; ++m)
#pragma unroll
          for (int n = 0; n < 2; ++n)
            acc[m][n] = __builtin_amdgcn_mfma_f32_16x16x32_bf16(af[m], bfv[n], acc[m][n], 0, 0, 0);
      }
      if (t < 7) WRITEA(sA + (cur ^ 1) * 4096)
      __syncthreads();
    }
#pragma unroll
    for (int m = 0; m < 2; ++m) {
      int r0 = m0 + wm * 32 + m * 16 + ((l >> 4) << 2);
#pragma unroll
      for (int nn = 0; nn < 2; ++nn) {
        int col = n0 + wn * 32 + nn * 16 + (l & 15);
        float bias = b_eff[col];
#pragma unroll
        for (int r = 0; r < 4; ++r)
          out[(size_t)(r0 + r) * DTOT + col] = acc[m][nn][r] + bias;
      }
    }
#undef LOADA
#undef WRITEA
#undef STAGEB
    return;
  }

  // ---- general: QKV projection GEMM ----
  if (bid >= 384) return;
  {
    bf16_t* sA = (bf16_t*)pool;
    bf16_t* sB = (bf16_t*)(pool + 8192);
    const int arow0 = (bid & 31) * 128, bcol0 = (bid >> 5) * 128;
    f32x4 acc[4][4];
#pragma unroll
    for (int m = 0; m < 4; ++m)
#pragma unroll
      for (int n = 0; n < 4; ++n) acc[m][n] = f32x4{0.f, 0.f, 0.f, 0.f};
    for (int kt = 0; kt < 512; kt += 32) {
#pragma unroll
      for (int i = 0; i < 2; ++i) {
        int row = (i << 6) + (w << 4) + (l >> 2);
        int cole = (l & 3) << 3;
        int ldso = i * 2048 + w * 512;
        async_copy16(&sA[ldso], &xb[(size_t)(arow0 + row) * 512 + kt + cole]);
        async_copy16(&sB[ldso], &wqkvT[(size_t)(bcol0 + row) * 512 + kt + cole]);
      }
      __syncthreads();
      bf16x8 af[4], bfr[4];
#pragma unroll
      for (int m = 0; m < 4; ++m)
        af[m] = *(const bf16x8*)&sA[(wm * 64 + m * 16 + (l & 15)) * 32 + ((l >> 4) << 3)];
#pragma unroll
      for (int n = 0; n < 4; ++n)
        bfr[n] = *(const bf16x8*)&sB[(wn * 64 + n * 16 + (l & 15)) * 32 + ((l >> 4) << 3)];
#pragma unroll
      for (int m = 0; m < 4; ++m)
#pragma unroll
        for (int n = 0; n < 4; ++n)
          acc[m][n] = __builtin_amdgcn_mfma_f32_16x16x32_bf16(af[m], bfr[n], acc[m][n], 0, 0, 0);
      __syncthreads();
    }
#pragma unroll
    for (int m = 0; m < 4; ++m) {
      int row0 = arow0 + wm * 64 + m * 16 + ((l >> 4) << 2);
#pragma unroll
      for (int n = 0; n < 4; ++n) {
        int col = bcol0 + wn * 64 + n * 16 + (l & 15);
        int mi = col >> 9, hc = col & 511;
        const float* bp = mi == 0 ? bq : mi == 1 ? bk : bv;
        float bias = bp[hc];
        int head = hc >> 6, tt = hc & 63;
        bf16_t* base = qkv + (((size_t)mi * NH + head) * NNODES) * DT + tt;
#pragma unroll
        for (int r = 0; r < 4; ++r)
          base[(size_t)(row0 + r) * DT] = (bf16_t)(acc[m][n][r] + bias);
      }
    }
  }
}

// ===========================================================================
// K3 (grid 256): GENERAL-ONLY flash attention (dead-launch when beta==0).
__global__ __launch_bounds__(256) void k3_attn(
    const bf16_t* __restrict__ qkv, const float* __restrict__ adj,
    const float* __restrict__ alpha, const float* __restrict__ beta,
    bf16_t* __restrict__ z) {
  if (beta_all_zero(beta)) return;
  __shared__ float qs[4][64];
  __shared__ float ps[4][64];
  const int wv_ = threadIdx.x >> 6;
  const int l = threadIdx.x & 63;
#pragma unroll
  for (int it = 0; it < 4; ++it) {
    int u = it * 256 + blockIdx.x;
    int h = u >> 7, bx = u & 127;
    const float a = alpha[h], b = beta[h];
    const size_t hoff = (size_t)h * NNODES * DT;
    const bf16_t* Q = qkv + hoff;
    const bf16_t* Kh = qkv + (size_t)NH * NNODES * DT + hoff;
    const bf16_t* V = qkv + (size_t)2 * NH * NNODES * DT + hoff;
    for (int i = bx * 4 + wv_; i < NNODES; i += 512) {
      if (b == 0.0f) {
        z[(size_t)i * DTOT + h * DT + l] = (bf16_t)(a * (float)V[(size_t)i * DT + l]);
        continue;
      }
      qs[wv_][l] = (float)Q[(size_t)i * DT + l];
      float mr = -__builtin_inff(), sr = 0.f, zacc = 0.f, sii = -__builtin_inff();
      const float* adjrow = adj + ((size_t)h * NNODES + i) * NNODES;
      __syncthreads();
      for (int c0 = 0; c0 < NNODES; c0 += 64) {
        int jj = c0 + l;
        float s = 0.f;
        const bf16_t* kp = Kh + (size_t)jj * DT;
#pragma unroll
        for (int d = 0; d < 64; ++d) s += qs[wv_][d] * (float)kp[d];
        s = s * 0.125f + adjrow[jj];
        if ((i >> 6) == (c0 >> 6)) sii = __shfl(s, i & 63, 64);
        float cm = s;
#pragma unroll
        for (int o = 32; o; o >>= 1) cm = fmaxf(cm, __shfl_xor(cm, o, 64));
        float mn = fmaxf(mr, cm);
        float scale = expf(mr - mn);
        sr *= scale;
        zacc *= scale;
        float p = expf(s - mn);
        float cs = p;
#pragma unroll
        for (int o = 32; o; o >>= 1) cs += __shfl_xor(cs, o, 64);
        sr += cs;
        mr = mn;
        ps[wv_][l] = p;
        __syncthreads();
        float za = 0.f;
        for (int j2 = 0; j2 < 64; ++j2)
          za += ps[wv_][j2] * (float)V[(size_t)(c0 + j2) * DT + l];
        zacc += za;
        __syncthreads();
      }
      float pii = expf(sii - mr) / sr;
      float vd = (float)V[(size_t)i * DT + l];
      float zd = b * (zacc / sr) + (a - b * pii) * vd;
      z[(size_t)i * DTOT + h * DT + l] = (bf16_t)zd;
    }
  }
}

// ===========================================================================
// K4 (grid 128): GENERAL-ONLY output GEMM: out = z @ woT^T + bo.
__global__ __launch_bounds__(256) void k4_outgemm(
    const bf16_t* __restrict__ z, const bf16_t* __restrict__ woT,
    const float* __restrict__ bo, const float* __restrict__ beta,
    float* __restrict__ out) {
  if (beta_all_zero(beta)) return;
  __shared__ __align__(16) bf16_t sA[128 * 32];
  __shared__ __align__(16) bf16_t sB[128 * 32];
  const int tid = threadIdx.x, l = tid & 63, w = tid >> 6;
  const int wm = w >> 1, wn = w & 1;
  const int arow0 = (blockIdx.x & 31) * 128, bcol0 = (blockIdx.x >> 5) * 128;
  f32x4 acc[4][4];
#pragma unroll
  for (int m = 0; m < 4; ++m)
#pragma unroll
    for (int n = 0; n < 4; ++n) acc[m][n] = f32x4{0.f, 0.f, 0.f, 0.f};
  for (int kt = 0; kt < 512; kt += 32) {
#pragma unroll
    for (int i = 0; i < 2; ++i) {
      int row = (i << 6) + (w << 4) + (l >> 2);
      int cole = (l & 3) << 3;
      int ldso = i * 2048 + w * 512;
      async_copy16(&sA[ldso], &z[(size_t)(arow0 + row) * 512 + kt + cole]);
      async_copy16(&sB[ldso], &woT[(size_t)(bcol0 + row) * 512 + kt + cole]);
    }
    __syncthreads();
    bf16x8 af[4], bfr[4];
#pragma unroll
    for (int m = 0; m < 4; ++m)
      af[m] = *(const bf16x8*)&sA[(wm * 64 + m * 16 + (l & 15)) * 32 + ((l >> 4) << 3)];
#pragma unroll
    for (int n = 0; n < 4; ++n)
      bfr[n] = *(const bf16x8*)&sB[(wn * 64 + n * 16 + (l & 15)) * 32 + ((l >> 4) << 3)];
#pragma unroll
    for (int m = 0; m < 4; ++m)
#pragma unroll
      for (int n = 0; n < 4; ++n)
        acc[m][n] = __builtin_amdgcn_mfma_f32_16x16x32_bf16(af[m], bfr[n], acc[m][n], 0, 0, 0);
    __syncthreads();
  }
#pragma unroll
  for (int m = 0; m < 4; ++m) {
    int row0 = arow0 + wm * 64 + m * 16 + ((l >> 4) << 2);
#pragma unroll
    for (int n = 0; n < 4; ++n) {
      int col = bcol0 + wn * 64 + n * 16 + (l & 15);
      float bias = bo[col];
#pragma unroll
      for (int r = 0; r < 4; ++r)
        out[(size_t)(row0 + r) * DTOT + col] = acc[m][n][r] + bias;
    }
  }
}

// ===========================================================================
extern "C" void kernel_launch(void* const* d_in, const int* in_sizes, int n_in,
                              void* d_out, int out_size, void* d_ws, size_t ws_size,
                              hipStream_t stream) {
  const float* x     = (const float*)d_in[0];
  const float* adj   = (const float*)d_in[1];
  const float* wq    = (const float*)d_in[2];
  const float* bq    = (const float*)d_in[3];
  const float* wk    = (const float*)d_in[4];
  const float* bk    = (const float*)d_in[5];
  const float* wv    = (const float*)d_in[6];
  const float* bv    = (const float*)d_in[7];
  const float* wo    = (const float*)d_in[8];
  const float* bo    = (const float*)d_in[9];
  const float* alpha = (const float*)d_in[10];
  const float* beta  = (const float*)d_in[11];
  float* out = (float*)d_out;
  char* ws = (char*)d_ws;

  bf16_t* xb     = (bf16_t*)(ws);                 // 4 MB
  bf16_t* wqkvT  = (bf16_t*)(ws + 4194304u);      // 1.5 MB
  bf16_t* woT    = (bf16_t*)(ws + 5767168u);      // 0.5 MB
  bf16_t* w_effT = (bf16_t*)(ws + 6291456u);      // 0.5 MB
  float*  b_eff  = (float*)(ws + 6815744u);       // 2 KB
  bf16_t* qkv    = (bf16_t*)(ws + 8388608u);      // 12 MB
  bf16_t* z      = (bf16_t*)(ws + 20971520u);     // 4 MB

  hipLaunchKernelGGL(k1_prep_compose, dim3(320), dim3(256), 0, stream,
                     x, wq, wk, wv, wo, bv, bo, alpha, beta,
                     xb, wqkvT, woT, w_effT, b_eff);
  hipLaunchKernelGGL(k2_final_qkv, dim3(512), dim3(256), 0, stream,
                     x, w_effT, b_eff, xb, wqkvT, bq, bk, bv, beta, out, qkv);
  hipLaunchKernelGGL(k3_attn, dim3(256), dim3(256), 0, stream,
                     qkv, adj, alpha, beta, z);
  hipLaunchKernelGGL(k4_outgemm, dim3(128), dim3(256), 0, stream,
                     z, woT, bo, beta, out);
}